// Round 11
// baseline (302.107 us; speedup 1.0000x reference)
//
#include <hip/hip_runtime.h>
#include <hip/hip_bf16.h>

// Problem constants (B=4, FEAT=256, H=W=48, NH=8, DK=DV=32, PE=10)
// I/O: all inputs fp32, output fp32 (verified round 7/8).
#define NTOK 2304

typedef short  short8  __attribute__((ext_vector_type(8)));   // 8 bf16 MFMA frag
typedef short  short4v __attribute__((ext_vector_type(4)));
typedef unsigned short ushort8v __attribute__((ext_vector_type(8)));
typedef float  f32x4   __attribute__((ext_vector_type(4)));

static __device__ __forceinline__ unsigned short f2bfu(float f){
  __hip_bfloat16 h = __float2bfloat16(f);          // RNE
  union { __hip_bfloat16 h; unsigned short u; } cv; cv.h = h; return cv.u;
}
// fast round-half-up bf16 pair pack (P-matrix only: unbiased, cheap)
static __device__ __forceinline__ unsigned pack2r(float a, float b){
  unsigned ua = __float_as_uint(a) + 0x8000u;
  unsigned ub = __float_as_uint(b) + 0x8000u;
  return (ua >> 16) | (ub & 0xFFFF0000u);
}

// ---------------- workspace layout ----------------
// ws[0..512)   float bns: sum[256], sumsq[256]
// ws[512..528) spare
// ushort arena at ws+528 (offsets in ushorts):
//   qT   @ 0         2654208 (4*2304*288) -> AO (attn out, tokmaj 256-wide)
//   kT   @ 2654208   2654208              -> h1 (tokmaj)
//   vT   @ 5308416   2359296              -> Ofc (fc out, tokmaj)
//   Qt   @ 7667712   2359296              -> Oc  (fc out, chanmaj)
//   Kt   @ 10027008  2359296  \__ pre (fp32 chanmaj) overlays Kt+V2 after attn
//   V2   @ 12386304  2359296  /
//   wqp  @ 14745600  73728   (pre-scaled by 1/sqrt(dk))
//   wkp  @ 14819328  73728   (pre-scaled by log2(e): scores in log2 domain)
//   wvb  @ 14893056  65536
//   wfcb @ 14958592  65536
//   w1b  @ 15024128  65536
//   w2b  @ 15089664  65536   (end 15155200)
// NEED = 2112 + 15155200*2 = 30,312,512 B

__global__ void trip_kernel(float* out, int n){
  int i = blockIdx.x*256 + threadIdx.x;
  if (i < n) out[i] = 1000.0f;   // sentinel: ws too small
}

// ---------------- fused setup: prep-transpose + PE + weight converts -------
// grid 3400 x 256:
//   [0,1728)    prep: fp32 [c][n] -> bf16 [n][c]
//   [1728,1800) pe_fill (72)
//   [1800,2376) padw (576): wq/wk -> padded 288; wq*1/sqrt(dk), wk*log2e
//   [2376,3400) convw (1024): wv/wfc/w1/w2 -> bf16
__global__ __launch_bounds__(256) void setup_kernel(
    const float* __restrict__ q, const float* __restrict__ k,
    const float* __restrict__ v,
    const float* __restrict__ wq, const float* __restrict__ wk,
    const float* __restrict__ wv, const float* __restrict__ wfc,
    const float* __restrict__ w1, const float* __restrict__ w2,
    unsigned short* __restrict__ qT, unsigned short* __restrict__ kT,
    unsigned short* __restrict__ vT,
    unsigned short* __restrict__ wqp, unsigned short* __restrict__ wkp,
    unsigned short* __restrict__ wvb, unsigned short* __restrict__ wfcb,
    unsigned short* __restrict__ w1b, unsigned short* __restrict__ w2b,
    float* __restrict__ bns){
  const int bid = blockIdx.x;
  const int t = threadIdx.x;
  __shared__ __align__(16) unsigned short tile[64*72];

  if (bid < 1728){                       // ---- prep transpose ----
    if (bid == 0){ bns[t] = 0.f; bns[256+t] = 0.f; }
    const int x = bid % 36, rem = bid / 36;
    const int y = rem % 4, z = rem / 4;  // z 0..11
    const int tz = z >> 2, b = z & 3;
    const float* src = (tz==0) ? q : ((tz==1) ? k : v);
    unsigned short* dst = (tz==0) ? qT : ((tz==1) ? kT : vT);
    const int W = (tz==2) ? 256 : 288;
    const int n0 = x*64, c0 = y*64;
    const int jj = t & 7, cl = t >> 3;   // 8 n-chunks x 32 c-rows
    #pragma unroll
    for (int p=0; p<2; p++){
      int c = c0 + 32*p + cl;
      const float* s = src + (size_t)(b*256 + c)*NTOK + n0 + 8*jj;
      float4 f0 = *(const float4*)s;
      float4 f1 = *(const float4*)(s + 4);
      unsigned short* tr = tile + 32*p + cl;
      tr[(8*jj+0)*72] = f2bfu(f0.x); tr[(8*jj+1)*72] = f2bfu(f0.y);
      tr[(8*jj+2)*72] = f2bfu(f0.z); tr[(8*jj+3)*72] = f2bfu(f0.w);
      tr[(8*jj+4)*72] = f2bfu(f1.x); tr[(8*jj+5)*72] = f2bfu(f1.y);
      tr[(8*jj+6)*72] = f2bfu(f1.z); tr[(8*jj+7)*72] = f2bfu(f1.w);
    }
    __syncthreads();
    #pragma unroll
    for (int p=0; p<2; p++){
      int nl = 32*p + cl;
      ushort8v val = *(const ushort8v*)(tile + nl*72 + 8*jj);
      *(ushort8v*)(dst + (size_t)(b*2304 + n0 + nl)*W + c0 + 8*jj) = val;
    }
  } else if (bid < 1800){                // ---- pe_fill ----
    const int id2 = bid - 1728;
    const int x = id2 % 9, yy = id2 / 9;
    const int n = x*256 + t;             // 0..2303
    unsigned short* buf = (yy < 4) ? qT : kT;
    const int b = yy & 3;
    const int i = n / 48, j = n - 48*i;
    const float k2pi = 6.283185307179586f;
    const float f = k2pi / 48.000001f;
    float ey = (float)(i+1) * f;
    float ex = (float)(j+1) * f;
    unsigned short u[32];
    #pragma unroll
    for (int p=0; p<10; p++){
      float inv = exp2f(-2.6575424759098898f * (float)(p >> 1));
      float vy = ey*inv, vx = ex*inv, vo = k2pi*inv;
      u[p]    = f2bfu((p&1) ? cosf(vy) : sinf(vy));
      u[10+p] = f2bfu((p&1) ? cosf(vx) : sinf(vx));
      u[20+p] = f2bfu((p&1) ? cosf(vo) : sinf(vo));
    }
    u[30] = 0; u[31] = 0;
    unsigned short* dst = buf + (size_t)(b*2304 + n)*288 + 256;
    #pragma unroll
    for (int m=0; m<4; m++) *(ushort8v*)(dst + 8*m) = *(const ushort8v*)(u + 8*m);
  } else if (bid < 2376){                // ---- padw ----
    const int id3 = bid - 1800;
    const int x = id3 % 288, y = id3 / 288;
    const int idx = x*256 + t;           // 0..73727
    const float* src = y ? wk : wq;
    unsigned short* dst = y ? wkp : wqp;
    // wq: 1/sqrt(32); wk: log2(e) so scores land in exp2 domain
    const float scale = y ? 1.4426950408889634f : 0.17677669529663689f;
    int row = idx / 288, col = idx - row*288;
    dst[idx] = (col < 286) ? f2bfu(src[row*286 + col] * scale) : (unsigned short)0;
  } else {                               // ---- convw ----
    const int id4 = bid - 2376;
    const int x = id4 % 256, y = id4 / 256;
    const int idx = x*256 + t;           // 0..65535
    const float* src = (y==0)?wv:((y==1)?wfc:((y==2)?w1:w2));
    unsigned short* dst = (y==0)?wvb:((y==1)?wfcb:((y==2)?w1b:w2b));
    dst[idx] = f2bfu(src[idx]);
  }
}

// ---------------- GEMM core: wave computes 16 tok x 32 oc ------------------
template<int KSTEPS>
static __device__ __forceinline__ void gemm_core(
    const unsigned short* __restrict__ arow,
    const unsigned short* __restrict__ wrow, int wstride, f32x4* acc){
  #pragma unroll
  for (int kk=0; kk<KSTEPS; kk++){
    short8 af = *(const short8*)(arow + 32*kk);
    #pragma unroll
    for (int to=0; to<2; to++){
      short8 bf = *(const short8*)(wrow + (size_t)(16*to)*wstride + 32*kk);
      acc[to] = __builtin_amdgcn_mfma_f32_16x16x32_bf16(af, bf, acc[to], 0,0,0);
    }
  }
}

// epilogue: token-major bf16 (wave-private LDS transpose; 16 tok x 32 oc)
static __device__ __forceinline__ void epi_tok(
    const f32x4* acc, unsigned short* __restrict__ out_tok,
    int b, int tok, int n0, int lane, int quad, int cc,
    unsigned short* __restrict__ tlw){
  #pragma unroll
  for (int to=0; to<2; to++)
    #pragma unroll
    for (int r=0; r<4; r++)
      tlw[(4*quad + r)*40 + 16*to + cc] = f2bfu(acc[to][r]);
  const int row = lane & 15, ch = lane >> 4;
  ushort8v val = *(const ushort8v*)(tlw + row*40 + 8*ch);
  *(ushort8v*)(out_tok + (size_t)(b*2304 + tok + row)*256 + n0 + 8*ch) = val;
}

// epilogue: channel-major bf16
static __device__ __forceinline__ void epi_chan(
    const f32x4* acc, unsigned short* __restrict__ out_chan,
    int b, int tok, int n0, int quad, int cc){
  #pragma unroll
  for (int to=0; to<2; to++){
    ushort4 pk;
    pk.x = f2bfu(acc[to][0]); pk.y = f2bfu(acc[to][1]);
    pk.z = f2bfu(acc[to][2]); pk.w = f2bfu(acc[to][3]);
    *(ushort4*)(out_chan + (size_t)(b*256 + n0 + 16*to + cc)*NTOK + tok + 4*quad) = pk;
  }
}

// ---------------- fused QKV projections ------------------------------------
// grid (36, 8, 12): x -> 64 tok, y -> 32 oc, z: tz = z>>2 (0=Q,1=K,2=V), b=z&3
__global__ __launch_bounds__(256) void qkv_kernel(
    const unsigned short* __restrict__ qT, const unsigned short* __restrict__ kT,
    const unsigned short* __restrict__ vT,
    const unsigned short* __restrict__ wqp, const unsigned short* __restrict__ wkp,
    const unsigned short* __restrict__ wvb,
    unsigned short* __restrict__ Qt, unsigned short* __restrict__ Kt,
    unsigned short* __restrict__ V2){
  const int t = threadIdx.x;
  const int w = t >> 6, lane = t & 63;
  const int quad = lane >> 4, cc = lane & 15;
  const int t0 = blockIdx.x*64, n0 = blockIdx.y*32;
  const int tz = blockIdx.z >> 2, b = blockIdx.z & 3;
  const int tok = t0 + 16*w;
  __shared__ __align__(16) unsigned short tl[4*16*40];
  unsigned short* tlw = tl + w*640;

  f32x4 acc[2];
  acc[0] = (f32x4){0.f,0.f,0.f,0.f}; acc[1] = acc[0];

  if (tz == 0){
    const unsigned short* arow = qT + (size_t)(b*2304 + tok + cc)*288 + 8*quad;
    const unsigned short* wrow = wqp + (size_t)(n0 + cc)*288 + 8*quad;
    gemm_core<9>(arow, wrow, 288, acc);
    epi_tok(acc, Qt, b, tok, n0, lane, quad, cc, tlw);
  } else if (tz == 1){
    const unsigned short* arow = kT + (size_t)(b*2304 + tok + cc)*288 + 8*quad;
    const unsigned short* wrow = wkp + (size_t)(n0 + cc)*288 + 8*quad;
    gemm_core<9>(arow, wrow, 288, acc);
    epi_tok(acc, Kt, b, tok, n0, lane, quad, cc, tlw);
  } else {
    const unsigned short* arow = vT + (size_t)(b*2304 + tok + cc)*256 + 8*quad;
    const unsigned short* wrow = wvb + (size_t)(n0 + cc)*256 + 8*quad;
    gemm_core<8>(arow, wrow, 256, acc);
    epi_chan(acc, V2, b, tok, n0, quad, cc);
  }
}

// ---------------- fc / ffn1 / ffn2 GEMMs (KSTEPS=8) ------------------------
// grid (36, 8, 4). EPI: 0 = tokmaj(+bias/relu), 2 = tok+chan, 3 = ffn2
template<int EPI>
__global__ __launch_bounds__(256) void gemm2_kernel(
    const unsigned short* __restrict__ aT,
    const unsigned short* __restrict__ wgt,
    const float* __restrict__ bias,
    unsigned short* __restrict__ out_tok,
    unsigned short* __restrict__ out_chan,
    const unsigned short* __restrict__ resid,
    float* __restrict__ pre_out, float* __restrict__ bns, int relu){
  const int t = threadIdx.x;
  const int w = t >> 6, lane = t & 63;
  const int quad = lane >> 4, cc = lane & 15;
  const int t0 = blockIdx.x*64, n0 = blockIdx.y*32, b = blockIdx.z;
  const int tok = t0 + 16*w;
  __shared__ __align__(16) unsigned short tl[4*16*40];
  unsigned short* tlw = tl + w*640;

  const unsigned short* arow = aT + (size_t)(b*2304 + tok + cc)*256 + 8*quad;
  const unsigned short* wrow = wgt + (size_t)(n0 + cc)*256 + 8*quad;
  f32x4 acc[2];
  acc[0] = (f32x4){0.f,0.f,0.f,0.f}; acc[1] = acc[0];
  gemm_core<8>(arow, wrow, 256, acc);

  if (bias){
    #pragma unroll
    for (int to=0; to<2; to++){
      float bv = bias[n0 + 16*to + cc];
      #pragma unroll
      for (int r=0; r<4; r++) acc[to][r] += bv;
    }
  }
  if (relu){
    #pragma unroll
    for (int to=0; to<2; to++)
      #pragma unroll
      for (int r=0; r<4; r++) acc[to][r] = fmaxf(acc[to][r], 0.f);
  }

  if (EPI == 2){
    epi_chan(acc, out_chan, b, tok, n0, quad, cc);
    epi_tok(acc, out_tok, b, tok, n0, lane, quad, cc, tlw);
  }
  if (EPI == 0){
    epi_tok(acc, out_tok, b, tok, n0, lane, quad, cc, tlw);
  }
  if (EPI == 3){                  // + residual (bf16 chanmaj), pre fp32, BN stats
    #pragma unroll
    for (int to=0; to<2; to++){
      size_t co = (size_t)(b*256 + n0 + 16*to + cc)*NTOK + tok + 4*quad;
      ushort4 rr = *(const ushort4*)(resid + co);
      float p0 = acc[to][0] + __uint_as_float((unsigned)rr.x << 16);
      float p1 = acc[to][1] + __uint_as_float((unsigned)rr.y << 16);
      float p2 = acc[to][2] + __uint_as_float((unsigned)rr.z << 16);
      float p3 = acc[to][3] + __uint_as_float((unsigned)rr.w << 16);
      *(float4*)(pre_out + co) = make_float4(p0,p1,p2,p3);
      float s1 = (p0+p1)+(p2+p3);
      float s2 = (p0*p0+p1*p1)+(p2*p2+p3*p3);
      s1 += __shfl_xor(s1, 16, 64); s1 += __shfl_xor(s1, 32, 64);
      s2 += __shfl_xor(s2, 16, 64); s2 += __shfl_xor(s2, 32, 64);
      if (quad == 0){
        atomicAdd(&bns[n0 + 16*to + cc],       s1);
        atomicAdd(&bns[256 + n0 + 16*to + cc], s2);
      }
    }
  }
}

// ---------------- attention: register-P MFMA flash -------------------------
// grid (72, 8, 4), block 256 = 4 waves; block owns 32 queries, wave owns a
// 576-key slice. KEY INSIGHT: S^T C-layout [key=4q+r][query=cc] equals the
// PV B-operand layout [k][n=cc] under the per-quad key permutation
// kappa(q,j) = j<4 ? 4q+j : 16+4q+(j-4). Loading V's A-fragment with the same
// permutation (two b64 loads) makes the exp'd scores directly usable as
// B-fragments -> NO LDS round-trip in the loop. Scores arrive in log2 domain
// (log2e folded into wk) -> native v_exp_f32.
__global__ __launch_bounds__(256) void attn_kernel(
    const unsigned short* __restrict__ Qt, const unsigned short* __restrict__ Kt,
    const unsigned short* __restrict__ V2, unsigned short* __restrict__ AO){
  const int t = threadIdx.x;
  const int w = t >> 6, lane = t & 63;
  const int quad = lane >> 4, cc = lane & 15;
  const int h = blockIdx.y, b = blockIdx.z;
  const int q0 = blockIdx.x*32;

  const unsigned short* qb = Qt + (size_t)(b*2304 + q0 + cc)*256 + h*32 + 8*quad;
  short8 qf0 = *(const short8*)(qb);
  short8 qf1 = *(const short8*)(qb + 16*256);

  const unsigned short* kb = Kt + (size_t)(b*2304 + cc)*256 + h*32 + 8*quad;
  const unsigned short* vb0 = V2 + (size_t)(b*256 + h*32 + cc)*NTOK;       // d=cc
  const unsigned short* vb1 = vb0 + (size_t)16*NTOK;                       // d=16+cc

  __shared__ __align__(16) unsigned short attn_lds[10240];   // merge only

  f32x4 o00 = {0.f,0.f,0.f,0.f}, o10 = o00, o01 = o00, o11 = o00;
  float lsum0 = 0.f, lsum1 = 0.f;

  const int kstart = w*576, kend = kstart + 576;
  short8 kf0 = *(const short8*)(kb + (size_t)kstart*256);
  short8 kf1 = *(const short8*)(kb + (size_t)(kstart+16)*256);
  // V permuted fragments: j<4 -> keys k0+4q+j ; j>=4 -> keys k0+16+4q+(j-4)
  short4v v0lo = *(const short4v*)(vb0 + kstart + 4*quad);
  short4v v0hi = *(const short4v*)(vb0 + kstart + 16 + 4*quad);
  short4v v1lo = *(const short4v*)(vb1 + kstart + 4*quad);
  short4v v1hi = *(const short4v*)(vb1 + kstart + 16 + 4*quad);

  #pragma unroll 1
  for (int k0 = kstart; k0 < kend; k0 += 32){
    int kn = (k0 + 32 < kend) ? k0 + 32 : kstart;    // harmless wrap prefetch
    short8 nk0 = *(const short8*)(kb + (size_t)kn*256);
    short8 nk1 = *(const short8*)(kb + (size_t)(kn+16)*256);
    short4v n0lo = *(const short4v*)(vb0 + kn + 4*quad);
    short4v n0hi = *(const short4v*)(vb0 + kn + 16 + 4*quad);
    short4v n1lo = *(const short4v*)(vb1 + kn + 4*quad);
    short4v n1hi = *(const short4v*)(vb1 + kn + 16 + 4*quad);

    f32x4 z = {0.f,0.f,0.f,0.f};
    f32x4 s00 = __builtin_amdgcn_mfma_f32_16x16x32_bf16(kf0, qf0, z, 0,0,0);
    f32x4 s10 = __builtin_amdgcn_mfma_f32_16x16x32_bf16(kf1, qf0, z, 0,0,0);
    f32x4 s01 = __builtin_amdgcn_mfma_f32_16x16x32_bf16(kf0, qf1, z, 0,0,0);
    f32x4 s11 = __builtin_amdgcn_mfma_f32_16x16x32_bf16(kf1, qf1, z, 0,0,0);

    #pragma unroll
    for (int r=0; r<4; r++){
      s00[r] = __builtin_amdgcn_exp2f(s00[r]);
      s10[r] = __builtin_amdgcn_exp2f(s10[r]);
      s01[r] = __builtin_amdgcn_exp2f(s01[r]);
      s11[r] = __builtin_amdgcn_exp2f(s11[r]);
    }
    lsum0 += ((s00[0]+s00[1])+(s00[2]+s00[3])) + ((s10[0]+s10[1])+(s10[2]+s10[3]));
    lsum1 += ((s01[0]+s01[1])+(s01[2]+s01[3])) + ((s11[0]+s11[1])+(s11[2]+s11[3]));

    // pack scores directly into B-fragments (key order = kappa)
    union { unsigned u[4]; short8 s; } pf0u, pf1u;
    pf0u.u[0] = pack2r(s00[0], s00[1]); pf0u.u[1] = pack2r(s00[2], s00[3]);
    pf0u.u[2] = pack2r(s10[0], s10[1]); pf0u.u[3] = pack2r(s10[2], s10[3]);
    pf1u.u[0] = pack2r(s01[0], s01[1]); pf1u.u[1] = pack2r(s01[2], s01[3]);
    pf1u.u[2] = pack2r(s11[0], s11[1]); pf1u.u[3] = pack2r(s11[2], s11[3]);

    // V A-fragments in the same permuted key order
    union { short4v h[2]; short8 s; } vf0u, vf1u;
    vf0u.h[0] = v0lo; vf0u.h[1] = v0hi;
    vf1u.h[0] = v1lo; vf1u.h[1] = v1hi;

    o00 = __builtin_amdgcn_mfma_f32_16x16x32_bf16(vf0u.s, pf0u.s, o00, 0,0,0);
    o10 = __builtin_amdgcn_mfma_f32_16x16x32_bf16(vf1u.s, pf0u.s, o10, 0,0,0);
    o01 = __builtin_amdgcn_mfma_f32_16x16x32_bf16(vf0u.s, pf1u.s, o01, 0,0,0);
    o11 = __builtin_amdgcn_mfma_f32_16x16x32_bf16(vf1u.s, pf1u.s, o11, 0,0,0);

    kf0 = nk0; kf1 = nk1;
    v0lo = n0lo; v0hi = n0hi; v1lo = n1lo; v1hi = n1hi;
  }

  // reduce lsum across quads (per query column cc)
  lsum0 += __shfl_xor(lsum0, 16, 64); lsum0 += __shfl_xor(lsum0, 32, 64);
  lsum1 += __shfl_xor(lsum1, 16, 64); lsum1 += __shfl_xor(lsum1, 32, 64);

  // ---- cross-wave merge: each wave writes its partials to its own region ---
  float* mg = (float*)(attn_lds + w*2560);   // 1280 floats per wave region
  {
    const int base = lane*17;                // stride 17: conflict-free
    #pragma unroll
    for (int i=0;i<4;i++){
      mg[base + i]      = o00[i];
      mg[base + 4 + i]  = o10[i];
      mg[base + 8 + i]  = o01[i];
      mg[base + 12 + i] = o11[i];
    }
    mg[1088 + lane] = lsum0;
    mg[1152 + lane] = lsum1;
  }
  __syncthreads();

  const float* m0 = (const float*)(attn_lds);
  const float* m1 = (const float*)(attn_lds + 2560);
  const float* m2 = (const float*)(attn_lds + 5120);
  const float* m3 = (const float*)(attn_lds + 7680);
  float ls0 = (m0[1088+lane]+m1[1088+lane]) + (m2[1088+lane]+m3[1088+lane]);
  float ls1 = (m0[1152+lane]+m1[1152+lane]) + (m2[1152+lane]+m3[1152+lane]);
  float inv = 1.f / ((w & 2) ? ls1 : ls0);

  const int off = lane*17 + w*4;             // wave w merges C-tile w
  float r0 = (m0[off+0]+m1[off+0]) + (m2[off+0]+m3[off+0]);
  float r1 = (m0[off+1]+m1[off+1]) + (m2[off+1]+m3[off+1]);
  float r2 = (m0[off+2]+m1[off+2]) + (m2[off+2]+m3[off+2]);
  float r3 = (m0[off+3]+m1[off+3]) + (m2[off+3]+m3[off+3]);

  const int qcol = q0 + ((w & 2) ? 16 : 0) + cc;
  const int dofs = (w & 1) ? 16 : 0;
  ushort4 pk;
  pk.x = f2bfu(r0*inv); pk.y = f2bfu(r1*inv);
  pk.z = f2bfu(r2*inv); pk.w = f2bfu(r3*inv);
  *(ushort4*)(AO + (size_t)(b*2304 + qcol)*256 + h*32 + dofs + 4*quad) = pk;
}

// ---------------- BatchNorm finalize: pre fp32 chanmaj -> fp32 out ---------
__global__ __launch_bounds__(256) void bn_final_kernel(
    const float* __restrict__ pre, const float* __restrict__ bns,
    const float* __restrict__ g, const float* __restrict__ bt,
    float* __restrict__ out){
  int i0 = (blockIdx.x*256 + threadIdx.x)*4;
  int ch = (i0 / NTOK) & 255;
  float mean = bns[ch] * (1.f/9216.f);
  float var  = bns[256+ch] * (1.f/9216.f) - mean*mean;
  float scl = g[ch] * rsqrtf(fmaxf(var, 0.f) + 1e-5f);
  float sh  = bt[ch] - mean*scl;
  float4 x = *(const float4*)(pre + i0);
  *(float4*)(out + i0) = make_float4(x.x*scl+sh, x.y*scl+sh, x.z*scl+sh, x.w*scl+sh);
}

// ---------------- launch ----------------
extern "C" void kernel_launch(void* const* d_in, const int* in_sizes, int n_in,
                              void* d_out, int out_size, void* d_ws, size_t ws_size,
                              hipStream_t stream){
  const size_t NEED = 2112 + (size_t)15155200*2;     // 30.3 MB
  if (ws_size < NEED){
    trip_kernel<<<dim3((out_size+255)/256), dim3(256), 0, stream>>>((float*)d_out, out_size);
    return;
  }
  const float* q   = (const float*)d_in[0];
  const float* k   = (const float*)d_in[1];
  const float* v   = (const float*)d_in[2];
  const float* wq  = (const float*)d_in[3];
  const float* wk  = (const float*)d_in[4];
  const float* wv  = (const float*)d_in[5];
  const float* wfc = (const float*)d_in[6];
  const float* w1  = (const float*)d_in[7];
  const float* b1  = (const float*)d_in[8];
  const float* w2  = (const float*)d_in[9];
  const float* b2  = (const float*)d_in[10];
  const float* gm  = (const float*)d_in[11];
  const float* bt  = (const float*)d_in[12];

  float* ws  = (float*)d_ws;
  float* bns = ws;
  unsigned short* ub = (unsigned short*)(ws + 528);
  unsigned short* u_qT = ub;                 // -> AO
  unsigned short* u_kT = ub + 2654208;       // -> h1
  unsigned short* u_vT = ub + 5308416;       // -> Ofc
  unsigned short* u_Qt = ub + 7667712;       // -> Oc
  unsigned short* u_Kt = ub + 10027008;      // -> pre (overlays Kt+V2)
  unsigned short* u_V2 = ub + 12386304;
  unsigned short* wqp  = ub + 14745600;
  unsigned short* wkp  = ub + 14819328;
  unsigned short* wvb  = ub + 14893056;
  unsigned short* wfcb = ub + 14958592;
  unsigned short* w1b  = ub + 15024128;
  unsigned short* w2b  = ub + 15089664;
  unsigned short* AO  = u_qT;
  unsigned short* h1  = u_kT;
  unsigned short* Ofc = u_vT;
  unsigned short* Oc  = u_Qt;
  float* pre = (float*)(u_Kt);

  setup_kernel<<<dim3(3400), dim3(256), 0, stream>>>(
      q, k, v, wq, wk, wv, wfc, w1, w2,
      u_qT, u_kT, u_vT, wqp, wkp, wvb, wfcb, w1b, w2b, bns);

  qkv_kernel<<<dim3(36,8,12), dim3(256), 0, stream>>>(u_qT, u_kT, u_vT, wqp, wkp, wvb, u_Qt, u_Kt, u_V2);

  attn_kernel<<<dim3(72,8,4), dim3(256), 0, stream>>>(u_Qt, u_Kt, u_V2, AO);

  gemm2_kernel<2><<<dim3(36,8,4), dim3(256), 0, stream>>>(AO,  wfcb, nullptr, Ofc, Oc, nullptr, nullptr, nullptr, 0);
  gemm2_kernel<0><<<dim3(36,8,4), dim3(256), 0, stream>>>(Ofc, w1b,  b1,      h1,  nullptr, nullptr, nullptr, nullptr, 1);
  gemm2_kernel<3><<<dim3(36,8,4), dim3(256), 0, stream>>>(h1,  w2b,  b2,      nullptr, nullptr, Oc, pre, bns, 0);

  bn_final_kernel<<<dim3(2304), dim3(256), 0, stream>>>(pre, bns, gm, bt, (float*)d_out);
}

// Round 12
// 275.707 us; speedup vs baseline: 1.0958x; 1.0958x over previous
//
#include <hip/hip_runtime.h>
#include <hip/hip_bf16.h>

// Problem constants (B=4, FEAT=256, H=W=48, NH=8, DK=DV=32, PE=10)
// I/O: all inputs fp32, output fp32 (verified round 7/8).
#define NTOK 2304

typedef short  short8  __attribute__((ext_vector_type(8)));   // 8 bf16 MFMA frag
typedef unsigned short ushort8v __attribute__((ext_vector_type(8)));
typedef float  f32x4   __attribute__((ext_vector_type(4)));

static __device__ __forceinline__ unsigned short f2bfu(float f){
  __hip_bfloat16 h = __float2bfloat16(f);          // RNE
  union { __hip_bfloat16 h; unsigned short u; } cv; cv.h = h; return cv.u;
}
// fast round-half-up bf16 pair pack (P-matrix only: unbiased, cheap)
static __device__ __forceinline__ unsigned pack2r(float a, float b){
  unsigned ua = __float_as_uint(a) + 0x8000u;
  unsigned ub = __float_as_uint(b) + 0x8000u;
  return (ua >> 16) | (ub & 0xFFFF0000u);
}

// ---------------- workspace layout ----------------
// ws[0..512)   float bns: sum[256], sumsq[256]
// ws[512..528) spare
// ushort arena at ws+528 (offsets in ushorts):
//   qT   @ 0         2654208 (4*2304*288) -> AO (attn out, tokmaj 256-wide)
//   kT   @ 2654208   2654208              -> h1 (tokmaj)
//   vT   @ 5308416   2359296              -> Ofc (fc out, tokmaj)
//   Qt   @ 7667712   2359296              -> Oc  (fc out, chanmaj)
//   Kt   @ 10027008  2359296  \__ pre (fp32 chanmaj) overlays Kt+V2 after attn
//   V2   @ 12386304  2359296  /
//   wqp  @ 14745600  73728   (pre-scaled by 1/sqrt(dk))
//   wkp  @ 14819328  73728   (pre-scaled by log2(e): scores in exp2 domain)
//   wvb  @ 14893056  65536
//   wfcb @ 14958592  65536
//   w1b  @ 15024128  65536
//   w2b  @ 15089664  65536   (end 15155200)
// NEED = 2112 + 15155200*2 = 30,312,512 B

__global__ void trip_kernel(float* out, int n){
  int i = blockIdx.x*256 + threadIdx.x;
  if (i < n) out[i] = 1000.0f;   // sentinel: ws too small
}

// ---------------- fused setup: prep-transpose + PE + weight converts -------
// grid 3400 x 256:
//   [0,1728)    prep: fp32 [c][n] -> bf16 [n][c]
//   [1728,1800) pe_fill (72)
//   [1800,2376) padw (576): wq/wk -> padded 288; wq*1/sqrt(dk), wk*log2e
//   [2376,3400) convw (1024): wv/wfc/w1/w2 -> bf16
__global__ __launch_bounds__(256) void setup_kernel(
    const float* __restrict__ q, const float* __restrict__ k,
    const float* __restrict__ v,
    const float* __restrict__ wq, const float* __restrict__ wk,
    const float* __restrict__ wv, const float* __restrict__ wfc,
    const float* __restrict__ w1, const float* __restrict__ w2,
    unsigned short* __restrict__ qT, unsigned short* __restrict__ kT,
    unsigned short* __restrict__ vT,
    unsigned short* __restrict__ wqp, unsigned short* __restrict__ wkp,
    unsigned short* __restrict__ wvb, unsigned short* __restrict__ wfcb,
    unsigned short* __restrict__ w1b, unsigned short* __restrict__ w2b,
    float* __restrict__ bns){
  const int bid = blockIdx.x;
  const int t = threadIdx.x;
  __shared__ __align__(16) unsigned short tile[64*72];

  if (bid < 1728){                       // ---- prep transpose ----
    if (bid == 0){ bns[t] = 0.f; bns[256+t] = 0.f; }
    const int x = bid % 36, rem = bid / 36;
    const int y = rem % 4, z = rem / 4;  // z 0..11
    const int tz = z >> 2, b = z & 3;
    const float* src = (tz==0) ? q : ((tz==1) ? k : v);
    unsigned short* dst = (tz==0) ? qT : ((tz==1) ? kT : vT);
    const int W = (tz==2) ? 256 : 288;
    const int n0 = x*64, c0 = y*64;
    const int jj = t & 7, cl = t >> 3;   // 8 n-chunks x 32 c-rows
    #pragma unroll
    for (int p=0; p<2; p++){
      int c = c0 + 32*p + cl;
      const float* s = src + (size_t)(b*256 + c)*NTOK + n0 + 8*jj;
      float4 f0 = *(const float4*)s;
      float4 f1 = *(const float4*)(s + 4);
      unsigned short* tr = tile + 32*p + cl;
      tr[(8*jj+0)*72] = f2bfu(f0.x); tr[(8*jj+1)*72] = f2bfu(f0.y);
      tr[(8*jj+2)*72] = f2bfu(f0.z); tr[(8*jj+3)*72] = f2bfu(f0.w);
      tr[(8*jj+4)*72] = f2bfu(f1.x); tr[(8*jj+5)*72] = f2bfu(f1.y);
      tr[(8*jj+6)*72] = f2bfu(f1.z); tr[(8*jj+7)*72] = f2bfu(f1.w);
    }
    __syncthreads();
    #pragma unroll
    for (int p=0; p<2; p++){
      int nl = 32*p + cl;
      ushort8v val = *(const ushort8v*)(tile + nl*72 + 8*jj);
      *(ushort8v*)(dst + (size_t)(b*2304 + n0 + nl)*W + c0 + 8*jj) = val;
    }
  } else if (bid < 1800){                // ---- pe_fill ----
    const int id2 = bid - 1728;
    const int x = id2 % 9, yy = id2 / 9;
    const int n = x*256 + t;             // 0..2303
    unsigned short* buf = (yy < 4) ? qT : kT;
    const int b = yy & 3;
    const int i = n / 48, j = n - 48*i;
    const float k2pi = 6.283185307179586f;
    const float f = k2pi / 48.000001f;
    float ey = (float)(i+1) * f;
    float ex = (float)(j+1) * f;
    unsigned short u[32];
    #pragma unroll
    for (int p=0; p<10; p++){
      float inv = exp2f(-2.6575424759098898f * (float)(p >> 1));
      float vy = ey*inv, vx = ex*inv, vo = k2pi*inv;
      u[p]    = f2bfu((p&1) ? cosf(vy) : sinf(vy));
      u[10+p] = f2bfu((p&1) ? cosf(vx) : sinf(vx));
      u[20+p] = f2bfu((p&1) ? cosf(vo) : sinf(vo));
    }
    u[30] = 0; u[31] = 0;
    unsigned short* dst = buf + (size_t)(b*2304 + n)*288 + 256;
    #pragma unroll
    for (int m=0; m<4; m++) *(ushort8v*)(dst + 8*m) = *(const ushort8v*)(u + 8*m);
  } else if (bid < 2376){                // ---- padw ----
    const int id3 = bid - 1800;
    const int x = id3 % 288, y = id3 / 288;
    const int idx = x*256 + t;           // 0..73727
    const float* src = y ? wk : wq;
    unsigned short* dst = y ? wkp : wqp;
    // wq: 1/sqrt(32); wk: log2(e) so scores land in exp2 domain
    const float scale = y ? 1.4426950408889634f : 0.17677669529663689f;
    int row = idx / 288, col = idx - row*288;
    dst[idx] = (col < 286) ? f2bfu(src[row*286 + col] * scale) : (unsigned short)0;
  } else {                               // ---- convw ----
    const int id4 = bid - 2376;
    const int x = id4 % 256, y = id4 / 256;
    const int idx = x*256 + t;           // 0..65535
    const float* src = (y==0)?wv:((y==1)?wfc:((y==2)?w1:w2));
    unsigned short* dst = (y==0)?wvb:((y==1)?wfcb:((y==2)?w1b:w2b));
    dst[idx] = f2bfu(src[idx]);
  }
}

// ---------------- GEMM core: wave computes 16 tok x 32 oc ------------------
template<int KSTEPS>
static __device__ __forceinline__ void gemm_core(
    const unsigned short* __restrict__ arow,
    const unsigned short* __restrict__ wrow, int wstride, f32x4* acc){
  #pragma unroll
  for (int kk=0; kk<KSTEPS; kk++){
    short8 af = *(const short8*)(arow + 32*kk);
    #pragma unroll
    for (int to=0; to<2; to++){
      short8 bf = *(const short8*)(wrow + (size_t)(16*to)*wstride + 32*kk);
      acc[to] = __builtin_amdgcn_mfma_f32_16x16x32_bf16(af, bf, acc[to], 0,0,0);
    }
  }
}

// epilogue: token-major bf16 (wave-private LDS transpose; 16 tok x 32 oc)
static __device__ __forceinline__ void epi_tok(
    const f32x4* acc, unsigned short* __restrict__ out_tok,
    int b, int tok, int n0, int lane, int quad, int cc,
    unsigned short* __restrict__ tlw){
  #pragma unroll
  for (int to=0; to<2; to++)
    #pragma unroll
    for (int r=0; r<4; r++)
      tlw[(4*quad + r)*40 + 16*to + cc] = f2bfu(acc[to][r]);
  const int row = lane & 15, ch = lane >> 4;
  ushort8v val = *(const ushort8v*)(tlw + row*40 + 8*ch);
  *(ushort8v*)(out_tok + (size_t)(b*2304 + tok + row)*256 + n0 + 8*ch) = val;
}

// epilogue: channel-major bf16
static __device__ __forceinline__ void epi_chan(
    const f32x4* acc, unsigned short* __restrict__ out_chan,
    int b, int tok, int n0, int quad, int cc){
  #pragma unroll
  for (int to=0; to<2; to++){
    ushort4 pk;
    pk.x = f2bfu(acc[to][0]); pk.y = f2bfu(acc[to][1]);
    pk.z = f2bfu(acc[to][2]); pk.w = f2bfu(acc[to][3]);
    *(ushort4*)(out_chan + (size_t)(b*256 + n0 + 16*to + cc)*NTOK + tok + 4*quad) = pk;
  }
}

// ---------------- fused QKV projections ------------------------------------
// grid (36, 8, 12): x -> 64 tok, y -> 32 oc, z: tz = z>>2 (0=Q,1=K,2=V), b=z&3
__global__ __launch_bounds__(256) void qkv_kernel(
    const unsigned short* __restrict__ qT, const unsigned short* __restrict__ kT,
    const unsigned short* __restrict__ vT,
    const unsigned short* __restrict__ wqp, const unsigned short* __restrict__ wkp,
    const unsigned short* __restrict__ wvb,
    unsigned short* __restrict__ Qt, unsigned short* __restrict__ Kt,
    unsigned short* __restrict__ V2){
  const int t = threadIdx.x;
  const int w = t >> 6, lane = t & 63;
  const int quad = lane >> 4, cc = lane & 15;
  const int t0 = blockIdx.x*64, n0 = blockIdx.y*32;
  const int tz = blockIdx.z >> 2, b = blockIdx.z & 3;
  const int tok = t0 + 16*w;
  __shared__ __align__(16) unsigned short tl[4*16*40];
  unsigned short* tlw = tl + w*640;

  f32x4 acc[2];
  acc[0] = (f32x4){0.f,0.f,0.f,0.f}; acc[1] = acc[0];

  if (tz == 0){
    const unsigned short* arow = qT + (size_t)(b*2304 + tok + cc)*288 + 8*quad;
    const unsigned short* wrow = wqp + (size_t)(n0 + cc)*288 + 8*quad;
    gemm_core<9>(arow, wrow, 288, acc);
    epi_tok(acc, Qt, b, tok, n0, lane, quad, cc, tlw);
  } else if (tz == 1){
    const unsigned short* arow = kT + (size_t)(b*2304 + tok + cc)*288 + 8*quad;
    const unsigned short* wrow = wkp + (size_t)(n0 + cc)*288 + 8*quad;
    gemm_core<9>(arow, wrow, 288, acc);
    epi_tok(acc, Kt, b, tok, n0, lane, quad, cc, tlw);
  } else {
    const unsigned short* arow = vT + (size_t)(b*2304 + tok + cc)*256 + 8*quad;
    const unsigned short* wrow = wvb + (size_t)(n0 + cc)*256 + 8*quad;
    gemm_core<8>(arow, wrow, 256, acc);
    epi_chan(acc, V2, b, tok, n0, quad, cc);
  }
}

// ---------------- fc / ffn1 / ffn2 GEMMs (KSTEPS=8) ------------------------
// grid (36, 8, 4). EPI: 0 = tokmaj(+bias/relu), 2 = tok+chan, 3 = ffn2
template<int EPI>
__global__ __launch_bounds__(256) void gemm2_kernel(
    const unsigned short* __restrict__ aT,
    const unsigned short* __restrict__ wgt,
    const float* __restrict__ bias,
    unsigned short* __restrict__ out_tok,
    unsigned short* __restrict__ out_chan,
    const unsigned short* __restrict__ resid,
    float* __restrict__ pre_out, float* __restrict__ bns, int relu){
  const int t = threadIdx.x;
  const int w = t >> 6, lane = t & 63;
  const int quad = lane >> 4, cc = lane & 15;
  const int t0 = blockIdx.x*64, n0 = blockIdx.y*32, b = blockIdx.z;
  const int tok = t0 + 16*w;
  __shared__ __align__(16) unsigned short tl[4*16*40];
  unsigned short* tlw = tl + w*640;

  const unsigned short* arow = aT + (size_t)(b*2304 + tok + cc)*256 + 8*quad;
  const unsigned short* wrow = wgt + (size_t)(n0 + cc)*256 + 8*quad;
  f32x4 acc[2];
  acc[0] = (f32x4){0.f,0.f,0.f,0.f}; acc[1] = acc[0];
  gemm_core<8>(arow, wrow, 256, acc);

  if (bias){
    #pragma unroll
    for (int to=0; to<2; to++){
      float bv = bias[n0 + 16*to + cc];
      #pragma unroll
      for (int r=0; r<4; r++) acc[to][r] += bv;
    }
  }
  if (relu){
    #pragma unroll
    for (int to=0; to<2; to++)
      #pragma unroll
      for (int r=0; r<4; r++) acc[to][r] = fmaxf(acc[to][r], 0.f);
  }

  if (EPI == 2){
    epi_chan(acc, out_chan, b, tok, n0, quad, cc);
    epi_tok(acc, out_tok, b, tok, n0, lane, quad, cc, tlw);
  }
  if (EPI == 0){
    epi_tok(acc, out_tok, b, tok, n0, lane, quad, cc, tlw);
  }
  if (EPI == 3){                  // + residual (bf16 chanmaj), pre fp32, BN stats
    #pragma unroll
    for (int to=0; to<2; to++){
      size_t co = (size_t)(b*256 + n0 + 16*to + cc)*NTOK + tok + 4*quad;
      ushort4 rr = *(const ushort4*)(resid + co);
      float p0 = acc[to][0] + __uint_as_float((unsigned)rr.x << 16);
      float p1 = acc[to][1] + __uint_as_float((unsigned)rr.y << 16);
      float p2 = acc[to][2] + __uint_as_float((unsigned)rr.z << 16);
      float p3 = acc[to][3] + __uint_as_float((unsigned)rr.w << 16);
      *(float4*)(pre_out + co) = make_float4(p0,p1,p2,p3);
      float s1 = (p0+p1)+(p2+p3);
      float s2 = (p0*p0+p1*p1)+(p2*p2+p3*p3);
      s1 += __shfl_xor(s1, 16, 64); s1 += __shfl_xor(s1, 32, 64);
      s2 += __shfl_xor(s2, 16, 64); s2 += __shfl_xor(s2, 32, 64);
      if (quad == 0){
        atomicAdd(&bns[n0 + 16*to + cc],       s1);
        atomicAdd(&bns[256 + n0 + 16*to + cc], s2);
      }
    }
  }
}

// ---------------- attention: key-split MFMA flash, XCD-clustered -----------
// grid (8, 72, 4): blockIdx.x = HEAD. HW assigns workgroup L -> XCD L%8
// (round-robin), and L%8 == h here, so all 288 blocks of head h land on the
// same XCD -> per-XCD K/V working set = 4*294KB = 1.2MB < 4MB L2.
// Block owns 32 queries; each of 4 waves handles a 576-key slice (18 iters).
// No-max softmax (exp2 domain; log2e folded into wk) => partial (O, lsum)
// merged by plain addition across waves. P via wave-private LDS.
__global__ __launch_bounds__(256) void attn_kernel(
    const unsigned short* __restrict__ Qt, const unsigned short* __restrict__ Kt,
    const unsigned short* __restrict__ V2, unsigned short* __restrict__ AO){
  const int t = threadIdx.x;
  const int w = t >> 6, lane = t & 63;
  const int quad = lane >> 4, cc = lane & 15;
  const int h = blockIdx.x, b = blockIdx.z;
  const int q0 = blockIdx.y*32;

  const unsigned short* qb = Qt + (size_t)(b*2304 + q0 + cc)*256 + h*32 + 8*quad;
  short8 qf0 = *(const short8*)(qb);
  short8 qf1 = *(const short8*)(qb + 16*256);

  const unsigned short* kb = Kt + (size_t)(b*2304 + cc)*256 + h*32 + 8*quad;
  const unsigned short* vb = V2 + (size_t)(b*256 + h*32 + cc)*NTOK + 8*quad;

  __shared__ __align__(16) unsigned short attn_lds[10240];   // 4 x 5KB regions
  unsigned short* Pl = attn_lds + w*2560;            // 32 rows x 40 ushorts

  f32x4 o00 = {0.f,0.f,0.f,0.f}, o10 = o00, o01 = o00, o11 = o00;
  float lsum0 = 0.f, lsum1 = 0.f;

  const int kstart = w*576, kend = kstart + 576;
  short8 kf0 = *(const short8*)(kb + (size_t)kstart*256);
  short8 kf1 = *(const short8*)(kb + (size_t)(kstart+16)*256);
  short8 vf0 = *(const short8*)(vb + kstart);
  short8 vf1 = *(const short8*)(vb + (size_t)16*NTOK + kstart);

  #pragma unroll 1
  for (int k0 = kstart; k0 < kend; k0 += 32){
    int kn = (k0 + 32 < kend) ? k0 + 32 : kstart;    // harmless wrap prefetch
    short8 nk0 = *(const short8*)(kb + (size_t)kn*256);
    short8 nk1 = *(const short8*)(kb + (size_t)(kn+16)*256);
    short8 nv0 = *(const short8*)(vb + kn);
    short8 nv1 = *(const short8*)(vb + (size_t)16*NTOK + kn);

    f32x4 z = {0.f,0.f,0.f,0.f};
    f32x4 s00 = __builtin_amdgcn_mfma_f32_16x16x32_bf16(kf0, qf0, z, 0,0,0);
    f32x4 s10 = __builtin_amdgcn_mfma_f32_16x16x32_bf16(kf1, qf0, z, 0,0,0);
    f32x4 s01 = __builtin_amdgcn_mfma_f32_16x16x32_bf16(kf0, qf1, z, 0,0,0);
    f32x4 s11 = __builtin_amdgcn_mfma_f32_16x16x32_bf16(kf1, qf1, z, 0,0,0);

    #pragma unroll
    for (int r=0; r<4; r++){
      s00[r] = __builtin_amdgcn_exp2f(s00[r]);
      s10[r] = __builtin_amdgcn_exp2f(s10[r]);
      s01[r] = __builtin_amdgcn_exp2f(s01[r]);
      s11[r] = __builtin_amdgcn_exp2f(s11[r]);
    }
    lsum0 += ((s00[0]+s00[1])+(s00[2]+s00[3])) + ((s10[0]+s10[1])+(s10[2]+s10[3]));
    lsum1 += ((s01[0]+s01[1])+(s01[2]+s01[3])) + ((s11[0]+s11[1])+(s11[2]+s11[3]));

    { uint2 pw; pw.x = pack2r(s00[0],s00[1]); pw.y = pack2r(s00[2],s00[3]);
      *(uint2*)(Pl + cc*40 + 4*quad) = pw; }
    { uint2 pw; pw.x = pack2r(s10[0],s10[1]); pw.y = pack2r(s10[2],s10[3]);
      *(uint2*)(Pl + cc*40 + 16 + 4*quad) = pw; }
    { uint2 pw; pw.x = pack2r(s01[0],s01[1]); pw.y = pack2r(s01[2],s01[3]);
      *(uint2*)(Pl + (16+cc)*40 + 4*quad) = pw; }
    { uint2 pw; pw.x = pack2r(s11[0],s11[1]); pw.y = pack2r(s11[2],s11[3]);
      *(uint2*)(Pl + (16+cc)*40 + 16 + 4*quad) = pw; }

    short8 pf0 = *(const short8*)(Pl + cc*40 + 8*quad);
    short8 pf1 = *(const short8*)(Pl + (16+cc)*40 + 8*quad);

    o00 = __builtin_amdgcn_mfma_f32_16x16x32_bf16(vf0, pf0, o00, 0,0,0);
    o10 = __builtin_amdgcn_mfma_f32_16x16x32_bf16(vf1, pf0, o10, 0,0,0);
    o01 = __builtin_amdgcn_mfma_f32_16x16x32_bf16(vf0, pf1, o01, 0,0,0);
    o11 = __builtin_amdgcn_mfma_f32_16x16x32_bf16(vf1, pf1, o11, 0,0,0);

    kf0 = nk0; kf1 = nk1; vf0 = nv0; vf1 = nv1;
  }

  // reduce lsum across quads (per query column cc)
  lsum0 += __shfl_xor(lsum0, 16, 64); lsum0 += __shfl_xor(lsum0, 32, 64);
  lsum1 += __shfl_xor(lsum1, 16, 64); lsum1 += __shfl_xor(lsum1, 32, 64);

  // ---- cross-wave merge: each wave writes its partials to its own region ---
  float* mg = (float*)(attn_lds + w*2560);   // 1280 floats per wave region
  {
    const int base = lane*17;                // stride 17: conflict-free
    #pragma unroll
    for (int i=0;i<4;i++){
      mg[base + i]      = o00[i];
      mg[base + 4 + i]  = o10[i];
      mg[base + 8 + i]  = o01[i];
      mg[base + 12 + i] = o11[i];
    }
    mg[1088 + lane] = lsum0;
    mg[1152 + lane] = lsum1;
  }
  __syncthreads();

  const float* m0 = (const float*)(attn_lds);
  const float* m1 = (const float*)(attn_lds + 2560);
  const float* m2 = (const float*)(attn_lds + 5120);
  const float* m3 = (const float*)(attn_lds + 7680);
  float ls0 = (m0[1088+lane]+m1[1088+lane]) + (m2[1088+lane]+m3[1088+lane]);
  float ls1 = (m0[1152+lane]+m1[1152+lane]) + (m2[1152+lane]+m3[1152+lane]);
  float inv = 1.f / ((w & 2) ? ls1 : ls0);

  const int off = lane*17 + w*4;             // wave w merges C-tile w
  float r0 = (m0[off+0]+m1[off+0]) + (m2[off+0]+m3[off+0]);
  float r1 = (m0[off+1]+m1[off+1]) + (m2[off+1]+m3[off+1]);
  float r2 = (m0[off+2]+m1[off+2]) + (m2[off+2]+m3[off+2]);
  float r3 = (m0[off+3]+m1[off+3]) + (m2[off+3]+m3[off+3]);

  const int qcol = q0 + ((w & 2) ? 16 : 0) + cc;
  const int dofs = (w & 1) ? 16 : 0;
  ushort4 pk;
  pk.x = f2bfu(r0*inv); pk.y = f2bfu(r1*inv);
  pk.z = f2bfu(r2*inv); pk.w = f2bfu(r3*inv);
  *(ushort4*)(AO + (size_t)(b*2304 + qcol)*256 + h*32 + dofs + 4*quad) = pk;
}

// ---------------- BatchNorm finalize: pre fp32 chanmaj -> fp32 out ---------
__global__ __launch_bounds__(256) void bn_final_kernel(
    const float* __restrict__ pre, const float* __restrict__ bns,
    const float* __restrict__ g, const float* __restrict__ bt,
    float* __restrict__ out){
  int i0 = (blockIdx.x*256 + threadIdx.x)*4;
  int ch = (i0 / NTOK) & 255;
  float mean = bns[ch] * (1.f/9216.f);
  float var  = bns[256+ch] * (1.f/9216.f) - mean*mean;
  float scl = g[ch] * rsqrtf(fmaxf(var, 0.f) + 1e-5f);
  float sh  = bt[ch] - mean*scl;
  float4 x = *(const float4*)(pre + i0);
  *(float4*)(out + i0) = make_float4(x.x*scl+sh, x.y*scl+sh, x.z*scl+sh, x.w*scl+sh);
}

// ---------------- launch ----------------
extern "C" void kernel_launch(void* const* d_in, const int* in_sizes, int n_in,
                              void* d_out, int out_size, void* d_ws, size_t ws_size,
                              hipStream_t stream){
  const size_t NEED = 2112 + (size_t)15155200*2;     // 30.3 MB
  if (ws_size < NEED){
    trip_kernel<<<dim3((out_size+255)/256), dim3(256), 0, stream>>>((float*)d_out, out_size);
    return;
  }
  const float* q   = (const float*)d_in[0];
  const float* k   = (const float*)d_in[1];
  const float* v   = (const float*)d_in[2];
  const float* wq  = (const float*)d_in[3];
  const float* wk  = (const float*)d_in[4];
  const float* wv  = (const float*)d_in[5];
  const float* wfc = (const float*)d_in[6];
  const float* w1  = (const float*)d_in[7];
  const float* b1  = (const float*)d_in[8];
  const float* w2  = (const float*)d_in[9];
  const float* b2  = (const float*)d_in[10];
  const float* gm  = (const float*)d_in[11];
  const float* bt  = (const float*)d_in[12];

  float* ws  = (float*)d_ws;
  float* bns = ws;
  unsigned short* ub = (unsigned short*)(ws + 528);
  unsigned short* u_qT = ub;                 // -> AO
  unsigned short* u_kT = ub + 2654208;       // -> h1
  unsigned short* u_vT = ub + 5308416;       // -> Ofc
  unsigned short* u_Qt = ub + 7667712;       // -> Oc
  unsigned short* u_Kt = ub + 10027008;      // -> pre (overlays Kt+V2)
  unsigned short* u_V2 = ub + 12386304;
  unsigned short* wqp  = ub + 14745600;
  unsigned short* wkp  = ub + 14819328;
  unsigned short* wvb  = ub + 14893056;
  unsigned short* wfcb = ub + 14958592;
  unsigned short* w1b  = ub + 15024128;
  unsigned short* w2b  = ub + 15089664;
  unsigned short* AO  = u_qT;
  unsigned short* h1  = u_kT;
  unsigned short* Ofc = u_vT;
  unsigned short* Oc  = u_Qt;
  float* pre = (float*)(u_Kt);

  setup_kernel<<<dim3(3400), dim3(256), 0, stream>>>(
      q, k, v, wq, wk, wv, wfc, w1, w2,
      u_qT, u_kT, u_vT, wqp, wkp, wvb, wfcb, w1b, w2b, bns);

  qkv_kernel<<<dim3(36,8,12), dim3(256), 0, stream>>>(u_qT, u_kT, u_vT, wqp, wkp, wvb, u_Qt, u_Kt, u_V2);

  attn_kernel<<<dim3(8,72,4), dim3(256), 0, stream>>>(u_Qt, u_Kt, u_V2, AO);

  gemm2_kernel<2><<<dim3(36,8,4), dim3(256), 0, stream>>>(AO,  wfcb, nullptr, Ofc, Oc, nullptr, nullptr, nullptr, 0);
  gemm2_kernel<0><<<dim3(36,8,4), dim3(256), 0, stream>>>(Ofc, w1b,  b1,      h1,  nullptr, nullptr, nullptr, nullptr, 1);
  gemm2_kernel<3><<<dim3(36,8,4), dim3(256), 0, stream>>>(h1,  w2b,  b2,      nullptr, nullptr, Oc, pre, bns, 0);

  bn_final_kernel<<<dim3(2304), dim3(256), 0, stream>>>(pre, bns, gm, bt, (float*)d_out);
}